// Round 2
// baseline (57.666 us; speedup 1.0000x reference)
//
#include <hip/hip_runtime.h>
#include <hip/hip_bf16.h>

#define A_N 8
#define C_N 256
#define H_N 80
#define W_N 108
#define P_N (H_N * W_N)      // 8640
#define O_N 7
#define MH 256               // mask H
#define MW 256               // mask W
#define OUT_HW 256
#define TILES ((P_N + 255) / 256)   // 34

__device__ __forceinline__ float sigmoidf_(float zv) {
    return 1.0f / (1.0f + __expf(-zv));
}

// ---------------------------------------------------------------------------
// Kernel 1: jax.image.resize(car_masks, (80,108), "bilinear") — antialias=True.
// Normalized triangle kernel with kernel_scale = in/out per dim.
// ---------------------------------------------------------------------------
__global__ void k_resize_cm(const float* __restrict__ masks, float* __restrict__ cm)
{
    int idx = blockIdx.x * blockDim.x + threadIdx.x;
    if (idx >= A_N * P_N) return;
    int a = idx / P_N, p = idx - a * P_N;
    int oy = p / W_N, ox = p - oy * W_N;

    const float ksy = 256.0f / 80.0f;    // inv_scale = kernel_scale (downsample, antialias)
    const float ksx = 256.0f / 108.0f;
    const float rky = 0.3125f;           // 80/256, exact
    const float rkx = 0.421875f;         // 108/256, exact

    float sfy = ((float)oy + 0.5f) * ksy - 0.5f;
    float sfx = ((float)ox + 0.5f) * ksx - 0.5f;
    int iy0 = max(0, (int)ceilf(sfy - ksy));
    int iy1 = min(MH - 1, (int)floorf(sfy + ksy));
    int ix0 = max(0, (int)ceilf(sfx - ksx));
    int ix1 = min(MW - 1, (int)floorf(sfx + ksx));

    float wys = 0.0f, wxs = 0.0f;
    for (int iy = iy0; iy <= iy1; ++iy)
        wys += fmaxf(0.0f, 1.0f - fabsf(sfy - (float)iy) * rky);
    for (int ix = ix0; ix <= ix1; ++ix)
        wxs += fmaxf(0.0f, 1.0f - fabsf(sfx - (float)ix) * rkx);

    const float* mp = masks + a * (MH * MW);
    float acc = 0.0f;
    for (int iy = iy0; iy <= iy1; ++iy) {
        float wyv = fmaxf(0.0f, 1.0f - fabsf(sfy - (float)iy) * rky);
        const float* row = mp + iy * MW;
        float racc = 0.0f;
        for (int ix = ix0; ix <= ix1; ++ix) {
            float wxv = fmaxf(0.0f, 1.0f - fabsf(sfx - (float)ix) * rkx);
            racc += wxv * row[ix];
        }
        acc += wyv * racc;
    }
    cm[idx] = acc / (wys * wxs);
}

// ---------------------------------------------------------------------------
// Kernel 2: z[a,o,p] = sum_c w[o,c]*x[a,c,p] + wsum[o]*cm[a,p]   (no bias)
//           ssolo[a,o,p] = sigmoid(z + b[o])
// Reads x (70.8 MB) once, coalesced across contiguous p. HBM-bound.
// ---------------------------------------------------------------------------
__launch_bounds__(256)
__global__ void k_conv(const float* __restrict__ x, const float* __restrict__ cm,
                       const float* __restrict__ w, const float* __restrict__ b,
                       float* __restrict__ z, float* __restrict__ ssolo)
{
    __shared__ float s_wsum[O_N];
    const int a    = blockIdx.x / TILES;
    const int tile = blockIdx.x - a * TILES;
    if (threadIdx.x < O_N) {
        float s = 0.0f;
        const float* wr = w + threadIdx.x * C_N;
        for (int c = 0; c < C_N; ++c) s += wr[c];
        s_wsum[threadIdx.x] = s;
    }
    __syncthreads();
    const int p = tile * 256 + threadIdx.x;
    if (p >= P_N) return;

    float acc[O_N];
    #pragma unroll
    for (int o = 0; o < O_N; ++o) acc[o] = 0.0f;

    const float* xp = x + (size_t)a * C_N * P_N + p;
    #pragma unroll 8
    for (int c = 0; c < C_N; ++c) {
        float v = xp[(size_t)c * P_N];
        #pragma unroll
        for (int o = 0; o < O_N; ++o)
            acc[o] = fmaf(w[o * C_N + c], v, acc[o]);
    }

    const float cmv = cm[a * P_N + p];
    const int zb = (a * O_N) * P_N + p;
    #pragma unroll
    for (int o = 0; o < O_N; ++o) {
        float zv = acc[o] + s_wsum[o] * cmv;
        z[zb + o * P_N]     = zv;
        ssolo[zb + o * P_N] = sigmoidf_(zv + b[o]);
    }
}

// ---------------------------------------------------------------------------
// Kernel 3: per ego i, pixel p: saggr = sigmoid(b + sum_j adj[i,j]!=0 ?
//           zero-padded-bilinear(z[j], rel[i,j] @ [u,v,1]) : 0)
// z planes total 1.9 MB — L2-resident gathers.
// ---------------------------------------------------------------------------
__global__ void k_aggr(const float* __restrict__ z, const float* __restrict__ rel,
                       const int* __restrict__ adj, const float* __restrict__ b,
                       float* __restrict__ saggr)
{
    int idx = blockIdx.x * blockDim.x + threadIdx.x;
    if (idx >= A_N * P_N) return;
    const int i = idx / P_N, p = idx - i * P_N;
    const int vy = p / W_N, ux = p - vy * W_N;
    const float fu = (float)ux, fv = (float)vy;

    float acc[O_N];
    #pragma unroll
    for (int o = 0; o < O_N; ++o) acc[o] = b[o];

    for (int j = 0; j < A_N; ++j) {
        if (adj[i * A_N + j] == 0) continue;
        const float* M = rel + (i * A_N + j) * 6;
        float sx = M[0] * fu + M[1] * fv + M[2];
        float sy = M[3] * fu + M[4] * fv + M[5];
        if (!(sx > -1.0f && sx < (float)W_N && sy > -1.0f && sy < (float)H_N)) continue;
        float x0f = floorf(sx), y0f = floorf(sy);
        float wx = sx - x0f, wy = sy - y0f;
        int x0 = (int)x0f, y0 = (int)y0f;
        int x1 = x0 + 1,  y1 = y0 + 1;
        float w00 = (1.0f - wy) * (1.0f - wx), w01 = (1.0f - wy) * wx;
        float w10 = wy * (1.0f - wx),          w11 = wy * wx;
        if (x0 < 0)    { w00 = 0.0f; w10 = 0.0f; x0 = 0; }
        if (x1 >= W_N) { w01 = 0.0f; w11 = 0.0f; x1 = W_N - 1; }
        if (y0 < 0)    { w00 = 0.0f; w01 = 0.0f; y0 = 0; }
        if (y1 >= H_N) { w10 = 0.0f; w11 = 0.0f; y1 = H_N - 1; }
        const int i00 = y0 * W_N + x0, i01 = y0 * W_N + x1;
        const int i10 = y1 * W_N + x0, i11 = y1 * W_N + x1;
        const float* zj = z + j * O_N * P_N;
        #pragma unroll
        for (int o = 0; o < O_N; ++o) {
            const float* zp = zj + o * P_N;
            acc[o] += w00 * zp[i00] + w01 * zp[i01] + w10 * zp[i10] + w11 * zp[i11];
        }
    }
    const int ob = i * O_N * P_N + p;
    #pragma unroll
    for (int o = 0; o < O_N; ++o) saggr[ob + o * P_N] = sigmoidf_(acc[o]);
}

// ---------------------------------------------------------------------------
// Kernel 4: align_corners=True bilinear 80x108 -> 256x256.
// Output is FLOAT32 (reference returns f32): [solo(8,7,256,256), aggr(...)].
// 2 px/thread -> float2 store (8 B/lane coalesced).
// ---------------------------------------------------------------------------
__global__ void k_upsample(const float* __restrict__ ssolo, const float* __restrict__ saggr,
                           float* __restrict__ out)
{
    int idx = blockIdx.x * blockDim.x + threadIdx.x;
    const int total = 2 * A_N * O_N * OUT_HW * (OUT_HW / 2);
    if (idx >= total) return;
    int k = idx;
    const int oxh = k & 127;  k >>= 7;
    const int oy  = k & 255;  k >>= 8;
    const int o   = k % O_N;  k /= O_N;
    const int a   = k & 7;    k >>= 3;
    const int t   = k;        // 0 = solo, 1 = aggr

    const float* src = (t == 0 ? ssolo : saggr) + (a * O_N + o) * P_N;
    float syf = (float)oy * (79.0f / 255.0f);
    int y0 = (int)syf; y0 = min(y0, H_N - 2);
    float wy = syf - (float)y0;
    const float* r0 = src + y0 * W_N;
    const float* r1 = r0 + W_N;

    float2 res;
    {
        int ox = oxh * 2;
        float sxf = (float)ox * (107.0f / 255.0f);
        int x0 = (int)sxf; x0 = min(x0, W_N - 2);
        float wx = sxf - (float)x0;
        float c0 = r0[x0]     * (1.0f - wy) + r1[x0]     * wy;
        float c1 = r0[x0 + 1] * (1.0f - wy) + r1[x0 + 1] * wy;
        res.x = c0 * (1.0f - wx) + c1 * wx;
    }
    {
        int ox = oxh * 2 + 1;
        float sxf = (float)ox * (107.0f / 255.0f);
        int x0 = (int)sxf; x0 = min(x0, W_N - 2);
        float wx = sxf - (float)x0;
        float c0 = r0[x0]     * (1.0f - wy) + r1[x0]     * wy;
        float c1 = r0[x0 + 1] * (1.0f - wy) + r1[x0 + 1] * wy;
        res.y = c0 * (1.0f - wx) + c1 * wx;
    }
    *reinterpret_cast<float2*>(out + (size_t)idx * 2) = res;
}

// ---------------------------------------------------------------------------
extern "C" void kernel_launch(void* const* d_in, const int* in_sizes, int n_in,
                              void* d_out, int out_size, void* d_ws, size_t ws_size,
                              hipStream_t stream)
{
    (void)in_sizes; (void)n_in; (void)out_size; (void)ws_size;
    const float* x    = (const float*)d_in[0];
    const float* rel  = (const float*)d_in[1];
    const int*   adj  = (const int*)d_in[2];
    const float* cmsk = (const float*)d_in[3];
    const float* wcls = (const float*)d_in[4];
    const float* bcls = (const float*)d_in[5];
    float* out = (float*)d_out;   // reference output dtype is float32

    float* ws    = (float*)d_ws;
    float* cm    = ws;                          // 8*8640            = 69,120 f32
    float* z     = cm    + A_N * P_N;           // 8*7*8640          = 483,840 f32
    float* ssolo = z     + A_N * O_N * P_N;     // 483,840 f32
    float* saggr = ssolo + A_N * O_N * P_N;     // 483,840 f32  (total ~6.1 MB)

    dim3 blk(256);
    k_resize_cm<<<(A_N * P_N + 255) / 256, blk, 0, stream>>>(cmsk, cm);
    k_conv<<<A_N * TILES, blk, 0, stream>>>(x, cm, wcls, bcls, z, ssolo);
    k_aggr<<<(A_N * P_N + 255) / 256, blk, 0, stream>>>(z, rel, adj, bcls, saggr);
    k_upsample<<<(2 * A_N * O_N * OUT_HW * (OUT_HW / 2) + 255) / 256, blk, 0, stream>>>(ssolo, saggr, out);
}